// Round 12
// baseline (249.492 us; speedup 1.0000x reference)
//
#include <hip/hip_runtime.h>

typedef unsigned short u16;
typedef __bf16 bf16;
typedef bf16 bf16x8 __attribute__((ext_vector_type(8)));
typedef float f32x4 __attribute__((ext_vector_type(4)));
typedef u16 u16x4 __attribute__((ext_vector_type(4)));
typedef u16 u16x8 __attribute__((ext_vector_type(8)));

#define MROWS 8192      // B*S
#define EDIM 768
#define NQKV 2304       // 3*E
#define NHEAD 12
#define DH 64
#define SEQ 1024
#define BATCH 8
#define BH 96           // BATCH*NHEAD
#define BHSD (BH * SEQ * DH)
#define KIT64 (EDIM / 64)   // 12

#if __has_builtin(__builtin_amdgcn_exp2f)
#define EXP2(x) __builtin_amdgcn_exp2f(x)
#else
#define EXP2(x) exp2f(x)
#endif

// float -> bf16 (native cvt on gfx950, RNE)
__device__ __forceinline__ u16 f2bf(float f) {
  bf16 b = (bf16)f;
  return __builtin_bit_cast(u16, b);
}

// async global->LDS, 16B per lane. LDS dest must be wave-uniform base + lane*16.
__device__ __forceinline__ void gload_lds16(const u16* g, u16* l) {
  __builtin_amdgcn_global_load_lds(
      (const __attribute__((address_space(1))) void*)g,
      (__attribute__((address_space(3))) void*)l, 16, 0, 0);
}

// ---------------- fused prep kernel ----------------
// Blocks 0..575: weight tile-transpose pack (LDS-bound). Blocks 576..6719:
// f32->bf16 convert of x (HBM-bound). Fusing removes one launch gap and runs
// the two phases concurrently (pack blocks ride along with the BW-bound cvt).
// Wt[n][e], n=region*768+h*64+d, equals W_region[h][e][d]. Wot[n][e]=Wo[e][n].
__global__ __launch_bounds__(256) void prep(
    const float* __restrict__ x, u16* __restrict__ xb,
    const float* __restrict__ Wq, const float* __restrict__ Wk,
    const float* __restrict__ Wv, const float* __restrict__ Wo,
    u16* __restrict__ Wt, u16* __restrict__ Wot) {
  int bid = blockIdx.x;
  int tid = threadIdx.x;
  if (bid >= 576) {                      // ---- cvt region ----
    int i = ((bid - 576) * 256 + tid) * 4;
    float4 v = *(const float4*)(x + i);
    u16x4 o;
    o[0] = f2bf(v.x); o[1] = f2bf(v.y); o[2] = f2bf(v.z); o[3] = f2bf(v.w);
    *(u16x4*)(xb + i) = o;
    return;
  }
  // ---- pack region (block-uniform branch; __syncthreads legal) ----
  __shared__ float T[64][65];
  int c = tid & 63, r4 = tid >> 6;    // 4 rows per pass, 16 passes
  if (bid < 432) {
    int region = bid / 144, rem = bid - region * 144;
    int h = rem / 12, e0 = (rem - h * 12) * 64;
    const float* W = region == 0 ? Wq : (region == 1 ? Wk : Wv);
    for (int p = 0; p < 16; p++) {
      int er = r4 + p * 4;
      T[er][c] = W[(size_t)(h * EDIM + e0 + er) * DH + c];   // coalesced read (d=c)
    }
    __syncthreads();
    int nbase = region * EDIM + h * 64;
    for (int p = 0; p < 16; p++) {
      int dr = r4 + p * 4;
      Wt[(size_t)(nbase + dr) * EDIM + e0 + c] = f2bf(T[c][dr]);  // coalesced write (e=c)
    }
  } else {
    int bo2 = bid - 432;
    int n0 = (bo2 / 12) * 64, e0 = (bo2 - (bo2 / 12) * 12) * 64;
    for (int p = 0; p < 16; p++) {
      int er = r4 + p * 4;
      T[er][c] = Wo[(size_t)(e0 + er) * EDIM + n0 + c];      // coalesced read (n=c)
    }
    __syncthreads();
    for (int p = 0; p < 16; p++) {
      int dr = r4 + p * 4;
      Wot[(size_t)(n0 + dr) * EDIM + e0 + c] = f2bf(T[c][dr]);
    }
  }
}

// ---------------- GEMM core: 2-barrier, global_load_lds staging ----------
// MEASURED-CLOSED structure lane for this shape (K=768): 128x128/4-wave optimum.
// 256x128/8-wave = -15% (R5); counted-vmcnt 64KB dbuf = -9% (R7: occupancy
// 4->2 blocks/CU loses more cross-block overlap than the pipeline gains).
// XOR swizzle (0 conflicts measured): element [row][c*8+j] at
// row*64 + ((c ^ (row&7))*8 + j); global_load_lds writes LDS LINEARLY, so the
// swizzle is applied on the GLOBAL SOURCE address (rule #21).
template <int BM, int BN, int NW>
__device__ __forceinline__ void gemm_core(
    const u16* __restrict__ A, const u16* __restrict__ Bt,
    u16* As, u16* Bs, int m0, int n0, int tid, f32x4 acc[4][4]) {
  constexpr int NT = NW * 64;
  constexpr int RPP = NT / 8;          // rows staged per gload pass
  constexpr int AP = BM / RPP;         // A passes
  constexpr int BP = BN / RPP;         // B passes
  constexpr int WMN = BM / 64;
  int wv = __builtin_amdgcn_readfirstlane(tid >> 6);
  int lane = tid & 63, quad = lane >> 4, l16 = lane & 15;
  int wm = (wv % WMN) * 64, wn = (wv / WMN) * 64;
  int srow = tid >> 3, cpos = tid & 7;
  int swcol = (cpos ^ (srow & 7)) * 8;       // inverse-swizzled source column
  const u16* Ag = A + (size_t)(m0 + srow) * EDIM + swcol;
  const u16* Bg = Bt + (size_t)(n0 + srow) * EDIM + swcol;
  u16* Asl = As + srow * 64 + cpos * 8;      // == tid*16B: wave base + lane*16B
  u16* Bsl = Bs + srow * 64 + cpos * 8;

  for (int k = 0; k < KIT64; k++) {
    __syncthreads();
    const u16* ak = Ag + k * 64;
    const u16* bk = Bg + k * 64;
#pragma unroll
    for (int p = 0; p < AP; p++)
      gload_lds16(ak + (size_t)(p * RPP) * EDIM, Asl + p * RPP * 64);
#pragma unroll
    for (int p = 0; p < BP; p++)
      gload_lds16(bk + (size_t)(p * RPP) * EDIM, Bsl + p * RPP * 64);
    __syncthreads();
#pragma unroll
    for (int kh = 0; kh < 2; kh++) {
      bf16x8 af[4], bfr[4];
      for (int i = 0; i < 4; i++) {
        int row = wm + i * 16 + l16;
        af[i] = *(const bf16x8*)(As + row * 64 + (((kh * 4 + quad) ^ (row & 7))) * 8);
      }
      for (int j = 0; j < 4; j++) {
        int row = wn + j * 16 + l16;
        bfr[j] = *(const bf16x8*)(Bs + row * 64 + (((kh * 4 + quad) ^ (row & 7))) * 8);
      }
      for (int i = 0; i < 4; i++)
        for (int j = 0; j < 4; j++)
          acc[i][j] = __builtin_amdgcn_mfma_f32_16x16x32_bf16(af[i], bfr[j], acc[i][j], 0, 0, 0);
    }
  }
}

// ---------------- GEMM 1: QKV projection (R6 proven form; clock-control kernel) ----
// XCD remap: lin%8 = XCD; each XCD owns 8 contiguous m-tiles x all 18 n-tiles.
__global__ __launch_bounds__(256, 4) void gemm_qkv(
    const u16* __restrict__ A, const u16* __restrict__ Bt,
    const float* __restrict__ bq, const float* __restrict__ bk, const float* __restrict__ bv,
    u16* __restrict__ qkv) {
  __shared__ __align__(16) u16 As[128 * 64];
  __shared__ __align__(16) u16 Bs[128 * 64];
  int tid = threadIdx.x;
  int wv = tid >> 6, lane = tid & 63, quad = lane >> 4, l16 = lane & 15;
  int wm = (wv & 1) * 64, wn = (wv >> 1) * 64;
  int lin = blockIdx.y * 64 + blockIdx.x;
  int xcd = lin & 7, r8 = lin >> 3;          // r8 in 0..143
  int m0 = (xcd * 8 + (r8 & 7)) * 128;
  int n0 = (r8 >> 3) * 128;                  // 0..17
  f32x4 acc[4][4] = {};
  gemm_core<128, 128, 4>(A, Bt, As, Bs, m0, n0, tid, acc);

  const float kQscale = 0.18033688011112042f; // (1/8) * log2(e)
  for (int i = 0; i < 4; i++) {
    int row0 = m0 + wm + i * 16 + quad * 4;
    for (int j = 0; j < 4; j++) {
      int n = n0 + wn + j * 16 + l16;
      int region = n / EDIM;
      int hd = n - region * EDIM;
      int h = hd >> 6, d = hd & 63;
      const float* bp = region == 0 ? bq : (region == 1 ? bk : bv);
      float bias = bp[hd];
      float scale = region == 0 ? kQscale : 1.0f;
      for (int r4 = 0; r4 < 4; r4++) {
        int rr = row0 + r4;
        int bb = rr >> 10, s = rr & 1023;
        float val = (acc[i][j][r4] + bias) * scale;
        u16 bv16 = f2bf(val);
        int bhh = bb * NHEAD + h;
        if (region < 2) {
          qkv[(size_t)region * BHSD + ((size_t)bhh * SEQ + s) * DH + d] = bv16;
        } else {
          qkv[(size_t)2 * BHSD + ((size_t)bhh * DH + d) * SEQ + s] = bv16;
        }
      }
    }
  }
}

// ---------------- flash attention: QBLK=128, L2-direct K/V, ZERO barriers ----------
// Guide m169 precedent (common-mistake #7): LDS-staging L2-resident data is pure
// overhead. Here each XCD's working set (12 heads x 256KB K/V = 3MB) is L2-resident
// (all 96 of the XCD's blocks run concurrently at 3 blocks/CU). So: read K/V
// fragments DIRECTLY from global (L2-hot) into registers. Deletes all staging,
// the double buffers, and EVERY __syncthreads -- LDS keeps only the per-wave Ps
// tile (wave-internal lgkmcnt ordering, compiler-emitted, as in R9). V-loads are
// hoisted to the tile top (T14 issue-early): their ~200cyc L2 latency hides under
// the QK+exp2+P phase. Coalescing: K rows are 128B; a kf read covers 64B x 16 rows.
// Tripwire: WRITE_SIZE must stay 12288 KiB (R2 spill lesson; VGPR rises to ~140).
__global__ __launch_bounds__(256, 3) void attn_kernel(const u16* __restrict__ qkv, u16* __restrict__ attn) {
  int lin = blockIdx.y * 96 + blockIdx.x;    // grid (96, 8)
  int xcd = lin & 7, rr = lin >> 3;          // rr in 0..95
  int bh = xcd * 12 + (rr >> 3);             // 12 heads per XCD
  int qt = rr & 7;
  int b = bh / NHEAD, h = bh - b * NHEAD;
  const u16* Q  = qkv + (size_t)bh * SEQ * DH;
  const u16* K  = qkv + (size_t)(BH + bh) * SEQ * DH;
  const u16* VT = qkv + (size_t)(2 * BH + bh) * SEQ * DH;  // [64][1024]
  int tid = threadIdx.x, wave = tid >> 6, lane = tid & 63, quad = lane >> 4, l16 = lane & 15;
  int q_base = qt * 128 + wave * 32;

  __shared__ __align__(16) u16 Ps[4][32 * 64];   // per wave P tile [q][t] swizzled (16KB)

  bf16x8 qf[2][2];
  for (int g = 0; g < 2; g++)
    for (int c = 0; c < 2; c++)
      qf[g][c] = *(const bf16x8*)(Q + (size_t)(q_base + g * 16 + l16) * DH + c * 32 + quad * 8);

  f32x4 o[2][4] = {};
  float psum[2][4] = {};   // per-lane partial row sums

  u16* P = Ps[wave];
  const u16* Kf = K + (size_t)l16 * DH + quad * 8;          // fragment base: row l16
  const u16* Vf = VT + (size_t)l16 * SEQ + quad * 8;        // fragment base: d-row l16

  for (int t0 = 0; t0 < SEQ; t0 += 64) {
    // issue-early V fragment loads (consumed by PV after the QK phase)
    bf16x8 vf[4][2];
#pragma unroll
    for (int n = 0; n < 4; n++) {
      vf[n][0] = *(const bf16x8*)(Vf + (size_t)(n * 16) * SEQ + t0);
      vf[n][1] = *(const bf16x8*)(Vf + (size_t)(n * 16) * SEQ + t0 + 32);
    }

    // scores + exp2; P written to LDS per-tc (R9-proven scalar writes, <=2-way)
    __builtin_amdgcn_s_setprio(1);
#pragma unroll
    for (int tc = 0; tc < 4; tc++) {
      const u16* kb = Kf + (size_t)(t0 + tc * 16) * DH;
      bf16x8 kf0 = *(const bf16x8*)(kb);
      bf16x8 kf1 = *(const bf16x8*)(kb + 32);
      int pc = tc * 2 + (l16 >> 3);
      for (int g = 0; g < 2; g++) {
        f32x4 z = {};
        z = __builtin_amdgcn_mfma_f32_16x16x32_bf16(qf[g][0], kf0, z, 0, 0, 0);
        z = __builtin_amdgcn_mfma_f32_16x16x32_bf16(qf[g][1], kf1, z, 0, 0, 0);
        for (int r = 0; r < 4; r++) {
          float pv = EXP2(z[r]);
          psum[g][r] += pv;
          int prow = g * 16 + quad * 4 + r;
          P[prow * 64 + ((pc ^ (prow & 7)) * 8) + (l16 & 7)] = f2bf(pv);
        }
      }
    }
    __builtin_amdgcn_s_setprio(0);

    bf16x8 pf[2][2];
#pragma unroll
    for (int g = 0; g < 2; g++)
      for (int kc = 0; kc < 2; kc++)
        pf[g][kc] = *(const bf16x8*)(P + (g * 16 + l16) * 64 + (((kc * 4 + quad) ^ (l16 & 7)) * 8));

    __builtin_amdgcn_s_setprio(1);
#pragma unroll
    for (int n = 0; n < 4; n++)
      for (int g = 0; g < 2; g++) {
        o[g][n] = __builtin_amdgcn_mfma_f32_16x16x32_bf16(pf[g][0], vf[n][0], o[g][n], 0, 0, 0);
        o[g][n] = __builtin_amdgcn_mfma_f32_16x16x32_bf16(pf[g][1], vf[n][1], o[g][n], 0, 0, 0);
      }
    __builtin_amdgcn_s_setprio(0);
    // no barrier: Ps is wave-private; K/V are read-only global
  }

  // finish row sums + normalize + store to attn [8192][768] bf16, col = h*64+d
  for (int g = 0; g < 2; g++) {
    for (int m = 1; m < 16; m <<= 1)
      for (int r = 0; r < 4; r++)
        psum[g][r] += __shfl_xor(psum[g][r], m);
    for (int r = 0; r < 4; r++) {
      float inv = 1.0f / psum[g][r];
      int qrow = q_base + g * 16 + quad * 4 + r;
      size_t rowoff = (size_t)(b * SEQ + qrow) * EDIM + h * DH;
      for (int n = 0; n < 4; n++)
        attn[rowoff + n * 16 + l16] = f2bf(o[g][n][r] * inv);
    }
  }
}

// ---------------- GEMM 3: output projection (unchanged) ----------------
__global__ __launch_bounds__(128, 3) void gemm_out(
    const u16* __restrict__ A, const u16* __restrict__ Bt,
    const float* __restrict__ bo, float* __restrict__ out) {
  __shared__ __align__(16) u16 As[64 * 64];
  __shared__ __align__(16) u16 Bs[128 * 64];
  int tid = threadIdx.x;
  int wv = tid >> 6, lane = tid & 63, quad = lane >> 4, l16 = lane & 15;
  int wn = wv * 64;                          // wave grid 1M x 2N; wm = 0
  int lin = blockIdx.y * 128 + blockIdx.x;
  int xcd = lin & 7, r = lin >> 3;           // r in 0..95
  int m0 = (xcd * 16 + (r & 15)) * 64;
  int n0 = (r >> 4) * 128;                   // 0..5
  f32x4 acc[4][4] = {};
  gemm_core<64, 128, 2>(A, Bt, As, Bs, m0, n0, tid, acc);

  for (int i = 0; i < 4; i++) {
    int row0 = m0 + i * 16 + quad * 4;
    for (int j = 0; j < 4; j++) {
      int n = n0 + wn + j * 16 + l16;
      float bias = bo[n];
      for (int r4 = 0; r4 < 4; r4++)
        out[(size_t)(row0 + r4) * EDIM + n] = acc[i][j][r4] + bias;
    }
  }
}

// ---------------- launch ----------------
extern "C" void kernel_launch(void* const* d_in, const int* in_sizes, int n_in,
                              void* d_out, int out_size, void* d_ws, size_t ws_size,
                              hipStream_t stream) {
  const float* x  = (const float*)d_in[0];
  const float* Wq = (const float*)d_in[1];
  const float* bq = (const float*)d_in[2];
  const float* Wk = (const float*)d_in[3];
  const float* bk = (const float*)d_in[4];
  const float* Wv = (const float*)d_in[5];
  const float* bv = (const float*)d_in[6];
  const float* Wo = (const float*)d_in[7];
  const float* bo = (const float*)d_in[8];
  float* out = (float*)d_out;
  char* ws = (char*)d_ws;

  u16* Xb   = (u16*)(ws);                      // 8192*768*2    = 12,582,912
  u16* Wt   = (u16*)(ws + 12582912);           // 2304*768*2    =  3,538,944
  u16* Wot  = (u16*)(ws + 16121856);           // 768*768*2     =  1,179,648
  u16* qkv  = (u16*)(ws + 17301504);           // 3*96*1024*64*2= 37,748,736
  u16* attn = (u16*)(ws + 55050240);           // 8192*768*2    = 12,582,912

  prep<<<6720, 256, 0, stream>>>(x, Xb, Wq, Wk, Wv, Wo, Wt, Wot);
  gemm_qkv<<<dim3(64, 18), 256, 0, stream>>>(Xb, Wt, bq, bk, bv, qkv);
  attn_kernel<<<dim3(96, 8), 256, 0, stream>>>(qkv, attn);
  gemm_out<<<dim3(128, 6), 128, 0, stream>>>(attn, Wot, bo, out);
}

// Round 13
// 197.937 us; speedup vs baseline: 1.2605x; 1.2605x over previous
//
#include <hip/hip_runtime.h>

typedef unsigned short u16;
typedef __bf16 bf16;
typedef bf16 bf16x8 __attribute__((ext_vector_type(8)));
typedef float f32x4 __attribute__((ext_vector_type(4)));
typedef u16 u16x4 __attribute__((ext_vector_type(4)));
typedef u16 u16x8 __attribute__((ext_vector_type(8)));

#define MROWS 8192      // B*S
#define EDIM 768
#define NQKV 2304       // 3*E
#define NHEAD 12
#define DH 64
#define SEQ 1024
#define BATCH 8
#define BH 96           // BATCH*NHEAD
#define BHSD (BH * SEQ * DH)
#define KIT64 (EDIM / 64)   // 12

#if __has_builtin(__builtin_amdgcn_exp2f)
#define EXP2(x) __builtin_amdgcn_exp2f(x)
#else
#define EXP2(x) exp2f(x)
#endif

// float -> bf16 (native cvt on gfx950, RNE)
__device__ __forceinline__ u16 f2bf(float f) {
  bf16 b = (bf16)f;
  return __builtin_bit_cast(u16, b);
}

// async global->LDS, 16B per lane. LDS dest must be wave-uniform base + lane*16.
__device__ __forceinline__ void gload_lds16(const u16* g, u16* l) {
  __builtin_amdgcn_global_load_lds(
      (const __attribute__((address_space(1))) void*)g,
      (__attribute__((address_space(3))) void*)l, 16, 0, 0);
}

// ---------------- fused prep kernel ----------------
// Blocks 0..575: weight tile-transpose pack (LDS-bound). Blocks 576..6719:
// f32->bf16 convert of x (HBM-bound). Fusing removes one launch gap and runs
// the two phases concurrently (pack blocks ride along with the BW-bound cvt).
// Wt[n][e], n=region*768+h*64+d, equals W_region[h][e][d]. Wot[n][e]=Wo[e][n].
__global__ __launch_bounds__(256) void prep(
    const float* __restrict__ x, u16* __restrict__ xb,
    const float* __restrict__ Wq, const float* __restrict__ Wk,
    const float* __restrict__ Wv, const float* __restrict__ Wo,
    u16* __restrict__ Wt, u16* __restrict__ Wot) {
  int bid = blockIdx.x;
  int tid = threadIdx.x;
  if (bid >= 576) {                      // ---- cvt region ----
    int i = ((bid - 576) * 256 + tid) * 4;
    float4 v = *(const float4*)(x + i);
    u16x4 o;
    o[0] = f2bf(v.x); o[1] = f2bf(v.y); o[2] = f2bf(v.z); o[3] = f2bf(v.w);
    *(u16x4*)(xb + i) = o;
    return;
  }
  // ---- pack region (block-uniform branch; __syncthreads legal) ----
  __shared__ float T[64][65];
  int c = tid & 63, r4 = tid >> 6;    // 4 rows per pass, 16 passes
  if (bid < 432) {
    int region = bid / 144, rem = bid - region * 144;
    int h = rem / 12, e0 = (rem - h * 12) * 64;
    const float* W = region == 0 ? Wq : (region == 1 ? Wk : Wv);
    for (int p = 0; p < 16; p++) {
      int er = r4 + p * 4;
      T[er][c] = W[(size_t)(h * EDIM + e0 + er) * DH + c];   // coalesced read (d=c)
    }
    __syncthreads();
    int nbase = region * EDIM + h * 64;
    for (int p = 0; p < 16; p++) {
      int dr = r4 + p * 4;
      Wt[(size_t)(nbase + dr) * EDIM + e0 + c] = f2bf(T[c][dr]);  // coalesced write (e=c)
    }
  } else {
    int bo2 = bid - 432;
    int n0 = (bo2 / 12) * 64, e0 = (bo2 - (bo2 / 12) * 12) * 64;
    for (int p = 0; p < 16; p++) {
      int er = r4 + p * 4;
      T[er][c] = Wo[(size_t)(e0 + er) * EDIM + n0 + c];      // coalesced read (n=c)
    }
    __syncthreads();
    for (int p = 0; p < 16; p++) {
      int dr = r4 + p * 4;
      Wot[(size_t)(n0 + dr) * EDIM + e0 + c] = f2bf(T[c][dr]);
    }
  }
}

// ---------------- GEMM core: 2-barrier, global_load_lds staging ----------
// MEASURED-CLOSED structure lane for this shape (K=768): 128x128/4-wave optimum.
// 256x128/8-wave = -15% (R5); counted-vmcnt 64KB dbuf = -9% (R7: occupancy
// 4->2 blocks/CU loses more cross-block overlap than the pipeline gains).
// XOR swizzle (0 conflicts measured): element [row][c*8+j] at
// row*64 + ((c ^ (row&7))*8 + j); global_load_lds writes LDS LINEARLY, so the
// swizzle is applied on the GLOBAL SOURCE address (rule #21).
template <int BM, int BN, int NW>
__device__ __forceinline__ void gemm_core(
    const u16* __restrict__ A, const u16* __restrict__ Bt,
    u16* As, u16* Bs, int m0, int n0, int tid, f32x4 acc[4][4]) {
  constexpr int NT = NW * 64;
  constexpr int RPP = NT / 8;          // rows staged per gload pass
  constexpr int AP = BM / RPP;         // A passes
  constexpr int BP = BN / RPP;         // B passes
  constexpr int WMN = BM / 64;
  int wv = __builtin_amdgcn_readfirstlane(tid >> 6);
  int lane = tid & 63, quad = lane >> 4, l16 = lane & 15;
  int wm = (wv % WMN) * 64, wn = (wv / WMN) * 64;
  int srow = tid >> 3, cpos = tid & 7;
  int swcol = (cpos ^ (srow & 7)) * 8;       // inverse-swizzled source column
  const u16* Ag = A + (size_t)(m0 + srow) * EDIM + swcol;
  const u16* Bg = Bt + (size_t)(n0 + srow) * EDIM + swcol;
  u16* Asl = As + srow * 64 + cpos * 8;      // == tid*16B: wave base + lane*16B
  u16* Bsl = Bs + srow * 64 + cpos * 8;

  for (int k = 0; k < KIT64; k++) {
    __syncthreads();
    const u16* ak = Ag + k * 64;
    const u16* bk = Bg + k * 64;
#pragma unroll
    for (int p = 0; p < AP; p++)
      gload_lds16(ak + (size_t)(p * RPP) * EDIM, Asl + p * RPP * 64);
#pragma unroll
    for (int p = 0; p < BP; p++)
      gload_lds16(bk + (size_t)(p * RPP) * EDIM, Bsl + p * RPP * 64);
    __syncthreads();
#pragma unroll
    for (int kh = 0; kh < 2; kh++) {
      bf16x8 af[4], bfr[4];
      for (int i = 0; i < 4; i++) {
        int row = wm + i * 16 + l16;
        af[i] = *(const bf16x8*)(As + row * 64 + (((kh * 4 + quad) ^ (row & 7))) * 8);
      }
      for (int j = 0; j < 4; j++) {
        int row = wn + j * 16 + l16;
        bfr[j] = *(const bf16x8*)(Bs + row * 64 + (((kh * 4 + quad) ^ (row & 7))) * 8);
      }
      for (int i = 0; i < 4; i++)
        for (int j = 0; j < 4; j++)
          acc[i][j] = __builtin_amdgcn_mfma_f32_16x16x32_bf16(af[i], bfr[j], acc[i][j], 0, 0, 0);
    }
  }
}

// ---------------- GEMM 1: QKV projection (R6 proven form) -------
// XCD remap: lin%8 = XCD; each XCD owns 8 contiguous m-tiles x all 18 n-tiles.
__global__ __launch_bounds__(256, 4) void gemm_qkv(
    const u16* __restrict__ A, const u16* __restrict__ Bt,
    const float* __restrict__ bq, const float* __restrict__ bk, const float* __restrict__ bv,
    u16* __restrict__ qkv) {
  __shared__ __align__(16) u16 As[128 * 64];
  __shared__ __align__(16) u16 Bs[128 * 64];
  int tid = threadIdx.x;
  int wv = tid >> 6, lane = tid & 63, quad = lane >> 4, l16 = lane & 15;
  int wm = (wv & 1) * 64, wn = (wv >> 1) * 64;
  int lin = blockIdx.y * 64 + blockIdx.x;
  int xcd = lin & 7, r8 = lin >> 3;          // r8 in 0..143
  int m0 = (xcd * 8 + (r8 & 7)) * 128;
  int n0 = (r8 >> 3) * 128;                  // 0..17
  f32x4 acc[4][4] = {};
  gemm_core<128, 128, 4>(A, Bt, As, Bs, m0, n0, tid, acc);

  const float kQscale = 0.18033688011112042f; // (1/8) * log2(e)
  for (int i = 0; i < 4; i++) {
    int row0 = m0 + wm + i * 16 + quad * 4;
    for (int j = 0; j < 4; j++) {
      int n = n0 + wn + j * 16 + l16;
      int region = n / EDIM;
      int hd = n - region * EDIM;
      int h = hd >> 6, d = hd & 63;
      const float* bp = region == 0 ? bq : (region == 1 ? bk : bv);
      float bias = bp[hd];
      float scale = region == 0 ? kQscale : 1.0f;
      for (int r4 = 0; r4 < 4; r4++) {
        int rr = row0 + r4;
        int bb = rr >> 10, s = rr & 1023;
        float val = (acc[i][j][r4] + bias) * scale;
        u16 bv16 = f2bf(val);
        int bhh = bb * NHEAD + h;
        if (region < 2) {
          qkv[(size_t)region * BHSD + ((size_t)bhh * SEQ + s) * DH + d] = bv16;
        } else {
          qkv[(size_t)2 * BHSD + ((size_t)bhh * DH + d) * SEQ + s] = bv16;
        }
      }
    }
  }
}

// ---------------- flash attention: QBLK=128 (measured-best R9/R11 form) -----------
// Lane history: async 2-phase staging ~neutral (R4); b64-packed P-writes -15%
// (R10: 4-way write conflict); L2-direct K/V -50% (R12: latency-bound, MfmaUtil
// 10%, every K/V fragment a dependent ~200cyc L2 load; gload_lds staging batches
// and amortizes that latency once per tile). This form is the measured optimum.
// Each wave owns 32 q-rows (2 groups of 16); every K/V fragment ds_read feeds two
// MFMAs; grid 768 = exactly 3 blocks/CU (LDS 48KB -> 3 resident).
// 2-phase async K/V staging via global_load_lds (rule #21 swizzle), 1 barrier/tile.
// Tripwire: WRITE_SIZE must stay 12288 KiB (R2 spill lesson).
__global__ __launch_bounds__(256, 3) void attn_kernel(const u16* __restrict__ qkv, u16* __restrict__ attn) {
  int lin = blockIdx.y * 96 + blockIdx.x;    // grid (96, 8)
  int xcd = lin & 7, rr = lin >> 3;          // rr in 0..95
  int bh = xcd * 12 + (rr >> 3);             // 12 heads per XCD
  int qt = rr & 7;
  int b = bh / NHEAD, h = bh - b * NHEAD;
  const u16* Q  = qkv + (size_t)bh * SEQ * DH;
  const u16* K  = qkv + (size_t)(BH + bh) * SEQ * DH;
  const u16* VT = qkv + (size_t)(2 * BH + bh) * SEQ * DH;  // [64][1024]
  int tid = threadIdx.x, wave = tid >> 6, lane = tid & 63, quad = lane >> 4, l16 = lane & 15;
  int q_base = qt * 128 + wave * 32;

  __shared__ __align__(16) u16 Ks[2][64 * 64];   // [t][d] swizzled, double-buffered
  __shared__ __align__(16) u16 Vts[2][64 * 64];  // [d][t] swizzled, double-buffered
  __shared__ __align__(16) u16 Ps[4][32 * 64];   // per wave P tile [q][t] swizzled

  bf16x8 qf[2][2];
  for (int g = 0; g < 2; g++)
    for (int c = 0; c < 2; c++)
      qf[g][c] = *(const bf16x8*)(Q + (size_t)(q_base + g * 16 + l16) * DH + c * 32 + quad * 8);

  f32x4 o[2][4] = {};
  float psum[2][4] = {};   // per-lane partial row sums

  int tr = tid >> 3, cpos = tid & 7;
  int ssw = (cpos ^ (tr & 7)) * 8;            // inverse-swizzled source chunk (u16)
  const u16* Kg0 = K + (size_t)tr * DH + ssw;
  const u16* Kg1 = K + (size_t)(tr + 32) * DH + ssw;
  const u16* Vg0 = VT + (size_t)tr * SEQ + ssw;
  const u16* Vg1 = VT + (size_t)(tr + 32) * SEQ + ssw;
  int dst0 = tr * 64 + cpos * 8;              // == tid*16B
  int dst1 = (tr + 32) * 64 + cpos * 8;

  // prologue: async-stage tile 0 into buffer 0
  gload_lds16(Kg0, Ks[0] + dst0);
  gload_lds16(Kg1, Ks[0] + dst1);
  gload_lds16(Vg0, Vts[0] + dst0);
  gload_lds16(Vg1, Vts[0] + dst1);
  __syncthreads();   // vmcnt(0) drain: tile 0 ready

  int buf = 0;
  u16* P = Ps[wave];
  for (int t0 = 0; t0 < SEQ; t0 += 64) {
    if (t0 + 64 < SEQ) {   // issue async loads for next tile into the other buffer
      int nb = buf ^ 1;
      gload_lds16(Kg0 + (size_t)(t0 + 64) * DH, Ks[nb] + dst0);
      gload_lds16(Kg1 + (size_t)(t0 + 64) * DH, Ks[nb] + dst1);
      gload_lds16(Vg0 + t0 + 64, Vts[nb] + dst0);
      gload_lds16(Vg1 + t0 + 64, Vts[nb] + dst1);
    }
    const u16* Kb = Ks[buf];
    const u16* Vb = Vts[buf];

    // scores + exp2; P written to LDS per-tc (keeps p liveness at 8 regs)
    __builtin_amdgcn_s_setprio(1);
    for (int tc = 0; tc < 4; tc++) {
      int krow = tc * 16 + l16, k7 = l16 & 7;
      bf16x8 kf0 = *(const bf16x8*)(Kb + krow * 64 + ((quad ^ k7) * 8));
      bf16x8 kf1 = *(const bf16x8*)(Kb + krow * 64 + (((4 + quad) ^ k7) * 8));
      int pc = tc * 2 + (l16 >> 3);
      for (int g = 0; g < 2; g++) {
        f32x4 z = {};
        z = __builtin_amdgcn_mfma_f32_16x16x32_bf16(qf[g][0], kf0, z, 0, 0, 0);
        z = __builtin_amdgcn_mfma_f32_16x16x32_bf16(qf[g][1], kf1, z, 0, 0, 0);
        for (int r = 0; r < 4; r++) {
          float pv = EXP2(z[r]);
          psum[g][r] += pv;
          int prow = g * 16 + quad * 4 + r;
          P[prow * 64 + ((pc ^ (prow & 7)) * 8) + (l16 & 7)] = f2bf(pv);
        }
      }
    }
    __builtin_amdgcn_s_setprio(0);

    bf16x8 pf[2][2];
    for (int g = 0; g < 2; g++)
      for (int kc = 0; kc < 2; kc++)
        pf[g][kc] = *(const bf16x8*)(P + (g * 16 + l16) * 64 + (((kc * 4 + quad) ^ (l16 & 7)) * 8));

    __builtin_amdgcn_s_setprio(1);
    for (int n = 0; n < 4; n++) {
      int vrow = n * 16 + l16, v7 = l16 & 7;
      bf16x8 vf0 = *(const bf16x8*)(Vb + vrow * 64 + ((quad ^ v7) * 8));
      bf16x8 vf1 = *(const bf16x8*)(Vb + vrow * 64 + (((4 + quad) ^ v7) * 8));
      for (int g = 0; g < 2; g++) {
        o[g][n] = __builtin_amdgcn_mfma_f32_16x16x32_bf16(pf[g][0], vf0, o[g][n], 0, 0, 0);
        o[g][n] = __builtin_amdgcn_mfma_f32_16x16x32_bf16(pf[g][1], vf1, o[g][n], 0, 0, 0);
      }
    }
    __builtin_amdgcn_s_setprio(0);

    __syncthreads();   // drains vmcnt(0): next tile landed; all waves done with buf
    buf ^= 1;
  }

  // finish row sums + normalize + store to attn [8192][768] bf16, col = h*64+d
  for (int g = 0; g < 2; g++) {
    for (int m = 1; m < 16; m <<= 1)
      for (int r = 0; r < 4; r++)
        psum[g][r] += __shfl_xor(psum[g][r], m);
    for (int r = 0; r < 4; r++) {
      float inv = 1.0f / psum[g][r];
      int qrow = q_base + g * 16 + quad * 4 + r;
      size_t rowoff = (size_t)(b * SEQ + qrow) * EDIM + h * DH;
      for (int n = 0; n < 4; n++)
        attn[rowoff + n * 16 + l16] = f2bf(o[g][n][r] * inv);
    }
  }
}

// ---------------- GEMM 3: output projection (unchanged) ----------------
__global__ __launch_bounds__(128, 3) void gemm_out(
    const u16* __restrict__ A, const u16* __restrict__ Bt,
    const float* __restrict__ bo, float* __restrict__ out) {
  __shared__ __align__(16) u16 As[64 * 64];
  __shared__ __align__(16) u16 Bs[128 * 64];
  int tid = threadIdx.x;
  int wv = tid >> 6, lane = tid & 63, quad = lane >> 4, l16 = lane & 15;
  int wn = wv * 64;                          // wave grid 1M x 2N; wm = 0
  int lin = blockIdx.y * 128 + blockIdx.x;
  int xcd = lin & 7, r = lin >> 3;           // r in 0..95
  int m0 = (xcd * 16 + (r & 15)) * 64;
  int n0 = (r >> 4) * 128;                   // 0..5
  f32x4 acc[4][4] = {};
  gemm_core<64, 128, 2>(A, Bt, As, Bs, m0, n0, tid, acc);

  for (int i = 0; i < 4; i++) {
    int row0 = m0 + i * 16 + quad * 4;
    for (int j = 0; j < 4; j++) {
      int n = n0 + wn + j * 16 + l16;
      float bias = bo[n];
      for (int r4 = 0; r4 < 4; r4++)
        out[(size_t)(row0 + r4) * EDIM + n] = acc[i][j][r4] + bias;
    }
  }
}

// ---------------- launch ----------------
extern "C" void kernel_launch(void* const* d_in, const int* in_sizes, int n_in,
                              void* d_out, int out_size, void* d_ws, size_t ws_size,
                              hipStream_t stream) {
  const float* x  = (const float*)d_in[0];
  const float* Wq = (const float*)d_in[1];
  const float* bq = (const float*)d_in[2];
  const float* Wk = (const float*)d_in[3];
  const float* bk = (const float*)d_in[4];
  const float* Wv = (const float*)d_in[5];
  const float* bv = (const float*)d_in[6];
  const float* Wo = (const float*)d_in[7];
  const float* bo = (const float*)d_in[8];
  float* out = (float*)d_out;
  char* ws = (char*)d_ws;

  u16* Xb   = (u16*)(ws);                      // 8192*768*2    = 12,582,912
  u16* Wt   = (u16*)(ws + 12582912);           // 2304*768*2    =  3,538,944
  u16* Wot  = (u16*)(ws + 16121856);           // 768*768*2     =  1,179,648
  u16* qkv  = (u16*)(ws + 17301504);           // 3*96*1024*64*2= 37,748,736
  u16* attn = (u16*)(ws + 55050240);           // 8192*768*2    = 12,582,912

  prep<<<6720, 256, 0, stream>>>(x, Xb, Wq, Wk, Wv, Wo, Wt, Wot);
  gemm_qkv<<<dim3(64, 18), 256, 0, stream>>>(Xb, Wt, bq, bk, bv, qkv);
  attn_kernel<<<dim3(96, 8), 256, 0, stream>>>(qkv, attn);
  gemm_out<<<dim3(128, 6), 128, 0, stream>>>(attn, Wot, bo, out);
}

// Round 14
// 192.160 us; speedup vs baseline: 1.2984x; 1.0301x over previous
//
#include <hip/hip_runtime.h>

typedef unsigned short u16;
typedef __bf16 bf16;
typedef bf16 bf16x8 __attribute__((ext_vector_type(8)));
typedef float f32x4 __attribute__((ext_vector_type(4)));
typedef u16 u16x4 __attribute__((ext_vector_type(4)));
typedef u16 u16x8 __attribute__((ext_vector_type(8)));

#define MROWS 8192      // B*S
#define EDIM 768
#define NQKV 2304       // 3*E
#define NHEAD 12
#define DH 64
#define SEQ 1024
#define BATCH 8
#define BH 96           // BATCH*NHEAD
#define BHSD (BH * SEQ * DH)
#define KIT64 (EDIM / 64)   // 12

#if __has_builtin(__builtin_amdgcn_exp2f)
#define EXP2(x) __builtin_amdgcn_exp2f(x)
#else
#define EXP2(x) exp2f(x)
#endif

// float -> bf16 (native cvt on gfx950, RNE)
__device__ __forceinline__ u16 f2bf(float f) {
  bf16 b = (bf16)f;
  return __builtin_bit_cast(u16, b);
}

// async global->LDS, 16B per lane. LDS dest must be wave-uniform base + lane*16.
__device__ __forceinline__ void gload_lds16(const u16* g, u16* l) {
  __builtin_amdgcn_global_load_lds(
      (const __attribute__((address_space(1))) void*)g,
      (__attribute__((address_space(3))) void*)l, 16, 0, 0);
}

// ---------------- fused prep kernel ----------------
// Blocks 0..575: weight tile-transpose pack (LDS-bound). Blocks 576..6719:
// f32->bf16 convert of x (HBM-bound). Fusing removes one launch gap and runs
// the two phases concurrently (pack blocks ride along with the BW-bound cvt).
// Wt[n][e], n=region*768+h*64+d, equals W_region[h][e][d]. Wot[n][e]=Wo[e][n].
__global__ __launch_bounds__(256) void prep(
    const float* __restrict__ x, u16* __restrict__ xb,
    const float* __restrict__ Wq, const float* __restrict__ Wk,
    const float* __restrict__ Wv, const float* __restrict__ Wo,
    u16* __restrict__ Wt, u16* __restrict__ Wot) {
  int bid = blockIdx.x;
  int tid = threadIdx.x;
  if (bid >= 576) {                      // ---- cvt region ----
    int i = ((bid - 576) * 256 + tid) * 4;
    float4 v = *(const float4*)(x + i);
    u16x4 o;
    o[0] = f2bf(v.x); o[1] = f2bf(v.y); o[2] = f2bf(v.z); o[3] = f2bf(v.w);
    *(u16x4*)(xb + i) = o;
    return;
  }
  // ---- pack region (block-uniform branch; __syncthreads legal) ----
  __shared__ float T[64][65];
  int c = tid & 63, r4 = tid >> 6;    // 4 rows per pass, 16 passes
  if (bid < 432) {
    int region = bid / 144, rem = bid - region * 144;
    int h = rem / 12, e0 = (rem - h * 12) * 64;
    const float* W = region == 0 ? Wq : (region == 1 ? Wk : Wv);
    for (int p = 0; p < 16; p++) {
      int er = r4 + p * 4;
      T[er][c] = W[(size_t)(h * EDIM + e0 + er) * DH + c];   // coalesced read (d=c)
    }
    __syncthreads();
    int nbase = region * EDIM + h * 64;
    for (int p = 0; p < 16; p++) {
      int dr = r4 + p * 4;
      Wt[(size_t)(nbase + dr) * EDIM + e0 + c] = f2bf(T[c][dr]);  // coalesced write (e=c)
    }
  } else {
    int bo2 = bid - 432;
    int n0 = (bo2 / 12) * 64, e0 = (bo2 - (bo2 / 12) * 12) * 64;
    for (int p = 0; p < 16; p++) {
      int er = r4 + p * 4;
      T[er][c] = Wo[(size_t)(e0 + er) * EDIM + n0 + c];      // coalesced read (n=c)
    }
    __syncthreads();
    for (int p = 0; p < 16; p++) {
      int dr = r4 + p * 4;
      Wot[(size_t)(n0 + dr) * EDIM + e0 + c] = f2bf(T[c][dr]);
    }
  }
}

// ---------------- GEMM core: 2-barrier, global_load_lds staging ----------
// MEASURED-CLOSED structure lane for this shape (K=768): 128x128/4-wave optimum.
// 256x128/8-wave = -15% (R5); counted-vmcnt 64KB dbuf = -9% (R7: occupancy
// 4->2 blocks/CU loses more cross-block overlap than the pipeline gains).
// XOR swizzle (0 conflicts measured): element [row][c*8+j] at
// row*64 + ((c ^ (row&7))*8 + j); global_load_lds writes LDS LINEARLY, so the
// swizzle is applied on the GLOBAL SOURCE address (rule #21).
template <int BM, int BN, int NW>
__device__ __forceinline__ void gemm_core(
    const u16* __restrict__ A, const u16* __restrict__ Bt,
    u16* As, u16* Bs, int m0, int n0, int tid, f32x4 acc[4][4]) {
  constexpr int NT = NW * 64;
  constexpr int RPP = NT / 8;          // rows staged per gload pass
  constexpr int AP = BM / RPP;         // A passes
  constexpr int BP = BN / RPP;         // B passes
  constexpr int WMN = BM / 64;
  int wv = __builtin_amdgcn_readfirstlane(tid >> 6);
  int lane = tid & 63, quad = lane >> 4, l16 = lane & 15;
  int wm = (wv % WMN) * 64, wn = (wv / WMN) * 64;
  int srow = tid >> 3, cpos = tid & 7;
  int swcol = (cpos ^ (srow & 7)) * 8;       // inverse-swizzled source column
  const u16* Ag = A + (size_t)(m0 + srow) * EDIM + swcol;
  const u16* Bg = Bt + (size_t)(n0 + srow) * EDIM + swcol;
  u16* Asl = As + srow * 64 + cpos * 8;      // == tid*16B: wave base + lane*16B
  u16* Bsl = Bs + srow * 64 + cpos * 8;

  for (int k = 0; k < KIT64; k++) {
    __syncthreads();
    const u16* ak = Ag + k * 64;
    const u16* bk = Bg + k * 64;
#pragma unroll
    for (int p = 0; p < AP; p++)
      gload_lds16(ak + (size_t)(p * RPP) * EDIM, Asl + p * RPP * 64);
#pragma unroll
    for (int p = 0; p < BP; p++)
      gload_lds16(bk + (size_t)(p * RPP) * EDIM, Bsl + p * RPP * 64);
    __syncthreads();
#pragma unroll
    for (int kh = 0; kh < 2; kh++) {
      bf16x8 af[4], bfr[4];
      for (int i = 0; i < 4; i++) {
        int row = wm + i * 16 + l16;
        af[i] = *(const bf16x8*)(As + row * 64 + (((kh * 4 + quad) ^ (row & 7))) * 8);
      }
      for (int j = 0; j < 4; j++) {
        int row = wn + j * 16 + l16;
        bfr[j] = *(const bf16x8*)(Bs + row * 64 + (((kh * 4 + quad) ^ (row & 7))) * 8);
      }
      for (int i = 0; i < 4; i++)
        for (int j = 0; j < 4; j++)
          acc[i][j] = __builtin_amdgcn_mfma_f32_16x16x32_bf16(af[i], bfr[j], acc[i][j], 0, 0, 0);
    }
  }
}

// ---------------- GEMM 1: QKV projection (R6 proven form; clock-control kernel) ----
// XCD remap: lin%8 = XCD; each XCD owns 8 contiguous m-tiles x all 18 n-tiles.
__global__ __launch_bounds__(256, 4) void gemm_qkv(
    const u16* __restrict__ A, const u16* __restrict__ Bt,
    const float* __restrict__ bq, const float* __restrict__ bk, const float* __restrict__ bv,
    u16* __restrict__ qkv) {
  __shared__ __align__(16) u16 As[128 * 64];
  __shared__ __align__(16) u16 Bs[128 * 64];
  int tid = threadIdx.x;
  int wv = tid >> 6, lane = tid & 63, quad = lane >> 4, l16 = lane & 15;
  int wm = (wv & 1) * 64, wn = (wv >> 1) * 64;
  int lin = blockIdx.y * 64 + blockIdx.x;
  int xcd = lin & 7, r8 = lin >> 3;          // r8 in 0..143
  int m0 = (xcd * 8 + (r8 & 7)) * 128;
  int n0 = (r8 >> 3) * 128;                  // 0..17
  f32x4 acc[4][4] = {};
  gemm_core<128, 128, 4>(A, Bt, As, Bs, m0, n0, tid, acc);

  const float kQscale = 0.18033688011112042f; // (1/8) * log2(e)
  for (int i = 0; i < 4; i++) {
    int row0 = m0 + wm + i * 16 + quad * 4;
    for (int j = 0; j < 4; j++) {
      int n = n0 + wn + j * 16 + l16;
      int region = n / EDIM;
      int hd = n - region * EDIM;
      int h = hd >> 6, d = hd & 63;
      const float* bp = region == 0 ? bq : (region == 1 ? bk : bv);
      float bias = bp[hd];
      float scale = region == 0 ? kQscale : 1.0f;
      for (int r4 = 0; r4 < 4; r4++) {
        int rr = row0 + r4;
        int bb = rr >> 10, s = rr & 1023;
        float val = (acc[i][j][r4] + bias) * scale;
        u16 bv16 = f2bf(val);
        int bhh = bb * NHEAD + h;
        if (region < 2) {
          qkv[(size_t)region * BHSD + ((size_t)bhh * SEQ + s) * DH + d] = bv16;
        } else {
          qkv[(size_t)2 * BHSD + ((size_t)bhh * DH + d) * SEQ + s] = bv16;
        }
      }
    }
  }
}

// ---------------- flash attention: QBLK=128 (R9 form, setprio REMOVED) -----------
// setprio removal rationale (T5 regime check, m190/m191): our block is 4-wave
// BARRIER-LOCKSTEP -- all waves hit the same phase together (m190's regime,
// where setprio measured -1.5%), not m191's independent-1-wave regime (+4-7%).
// With no wave role-diversity inside the block, priority boosts only distort
// scheduling against the other 2 resident blocks (the latency-hiding resource).
// Lane history: async 2-phase staging ~neutral (R4); b64-packed P-writes -15%
// (R10: 4-way write conflict); L2-direct K/V -50% (R12: latency-bound).
// Each wave owns 32 q-rows (2 groups of 16); every K/V fragment ds_read feeds two
// MFMAs; grid 768 = exactly 3 blocks/CU (LDS 48KB -> 3 resident).
// 2-phase async K/V staging via global_load_lds (rule #21 swizzle), 1 barrier/tile.
// Tripwire: WRITE_SIZE must stay 12288 KiB (R2 spill lesson).
__global__ __launch_bounds__(256, 3) void attn_kernel(const u16* __restrict__ qkv, u16* __restrict__ attn) {
  int lin = blockIdx.y * 96 + blockIdx.x;    // grid (96, 8)
  int xcd = lin & 7, rr = lin >> 3;          // rr in 0..95
  int bh = xcd * 12 + (rr >> 3);             // 12 heads per XCD
  int qt = rr & 7;
  int b = bh / NHEAD, h = bh - b * NHEAD;
  const u16* Q  = qkv + (size_t)bh * SEQ * DH;
  const u16* K  = qkv + (size_t)(BH + bh) * SEQ * DH;
  const u16* VT = qkv + (size_t)(2 * BH + bh) * SEQ * DH;  // [64][1024]
  int tid = threadIdx.x, wave = tid >> 6, lane = tid & 63, quad = lane >> 4, l16 = lane & 15;
  int q_base = qt * 128 + wave * 32;

  __shared__ __align__(16) u16 Ks[2][64 * 64];   // [t][d] swizzled, double-buffered
  __shared__ __align__(16) u16 Vts[2][64 * 64];  // [d][t] swizzled, double-buffered
  __shared__ __align__(16) u16 Ps[4][32 * 64];   // per wave P tile [q][t] swizzled

  bf16x8 qf[2][2];
  for (int g = 0; g < 2; g++)
    for (int c = 0; c < 2; c++)
      qf[g][c] = *(const bf16x8*)(Q + (size_t)(q_base + g * 16 + l16) * DH + c * 32 + quad * 8);

  f32x4 o[2][4] = {};
  float psum[2][4] = {};   // per-lane partial row sums

  int tr = tid >> 3, cpos = tid & 7;
  int ssw = (cpos ^ (tr & 7)) * 8;            // inverse-swizzled source chunk (u16)
  const u16* Kg0 = K + (size_t)tr * DH + ssw;
  const u16* Kg1 = K + (size_t)(tr + 32) * DH + ssw;
  const u16* Vg0 = VT + (size_t)tr * SEQ + ssw;
  const u16* Vg1 = VT + (size_t)(tr + 32) * SEQ + ssw;
  int dst0 = tr * 64 + cpos * 8;              // == tid*16B
  int dst1 = (tr + 32) * 64 + cpos * 8;

  // prologue: async-stage tile 0 into buffer 0
  gload_lds16(Kg0, Ks[0] + dst0);
  gload_lds16(Kg1, Ks[0] + dst1);
  gload_lds16(Vg0, Vts[0] + dst0);
  gload_lds16(Vg1, Vts[0] + dst1);
  __syncthreads();   // vmcnt(0) drain: tile 0 ready

  int buf = 0;
  u16* P = Ps[wave];
  for (int t0 = 0; t0 < SEQ; t0 += 64) {
    if (t0 + 64 < SEQ) {   // issue async loads for next tile into the other buffer
      int nb = buf ^ 1;
      gload_lds16(Kg0 + (size_t)(t0 + 64) * DH, Ks[nb] + dst0);
      gload_lds16(Kg1 + (size_t)(t0 + 64) * DH, Ks[nb] + dst1);
      gload_lds16(Vg0 + t0 + 64, Vts[nb] + dst0);
      gload_lds16(Vg1 + t0 + 64, Vts[nb] + dst1);
    }
    const u16* Kb = Ks[buf];
    const u16* Vb = Vts[buf];

    // scores + exp2; P written to LDS per-tc (keeps p liveness at 8 regs)
    for (int tc = 0; tc < 4; tc++) {
      int krow = tc * 16 + l16, k7 = l16 & 7;
      bf16x8 kf0 = *(const bf16x8*)(Kb + krow * 64 + ((quad ^ k7) * 8));
      bf16x8 kf1 = *(const bf16x8*)(Kb + krow * 64 + (((4 + quad) ^ k7) * 8));
      int pc = tc * 2 + (l16 >> 3);
      for (int g = 0; g < 2; g++) {
        f32x4 z = {};
        z = __builtin_amdgcn_mfma_f32_16x16x32_bf16(qf[g][0], kf0, z, 0, 0, 0);
        z = __builtin_amdgcn_mfma_f32_16x16x32_bf16(qf[g][1], kf1, z, 0, 0, 0);
        for (int r = 0; r < 4; r++) {
          float pv = EXP2(z[r]);
          psum[g][r] += pv;
          int prow = g * 16 + quad * 4 + r;
          P[prow * 64 + ((pc ^ (prow & 7)) * 8) + (l16 & 7)] = f2bf(pv);
        }
      }
    }

    bf16x8 pf[2][2];
    for (int g = 0; g < 2; g++)
      for (int kc = 0; kc < 2; kc++)
        pf[g][kc] = *(const bf16x8*)(P + (g * 16 + l16) * 64 + (((kc * 4 + quad) ^ (l16 & 7)) * 8));

    for (int n = 0; n < 4; n++) {
      int vrow = n * 16 + l16, v7 = l16 & 7;
      bf16x8 vf0 = *(const bf16x8*)(Vb + vrow * 64 + ((quad ^ v7) * 8));
      bf16x8 vf1 = *(const bf16x8*)(Vb + vrow * 64 + (((4 + quad) ^ v7) * 8));
      for (int g = 0; g < 2; g++) {
        o[g][n] = __builtin_amdgcn_mfma_f32_16x16x32_bf16(pf[g][0], vf0, o[g][n], 0, 0, 0);
        o[g][n] = __builtin_amdgcn_mfma_f32_16x16x32_bf16(pf[g][1], vf1, o[g][n], 0, 0, 0);
      }
    }

    __syncthreads();   // drains vmcnt(0): next tile landed; all waves done with buf
    buf ^= 1;
  }

  // finish row sums + normalize + store to attn [8192][768] bf16, col = h*64+d
  for (int g = 0; g < 2; g++) {
    for (int m = 1; m < 16; m <<= 1)
      for (int r = 0; r < 4; r++)
        psum[g][r] += __shfl_xor(psum[g][r], m);
    for (int r = 0; r < 4; r++) {
      float inv = 1.0f / psum[g][r];
      int qrow = q_base + g * 16 + quad * 4 + r;
      size_t rowoff = (size_t)(b * SEQ + qrow) * EDIM + h * DH;
      for (int n = 0; n < 4; n++)
        attn[rowoff + n * 16 + l16] = f2bf(o[g][n][r] * inv);
    }
  }
}

// ---------------- GEMM 3: output projection (unchanged) ----------------
__global__ __launch_bounds__(128, 3) void gemm_out(
    const u16* __restrict__ A, const u16* __restrict__ Bt,
    const float* __restrict__ bo, float* __restrict__ out) {
  __shared__ __align__(16) u16 As[64 * 64];
  __shared__ __align__(16) u16 Bs[128 * 64];
  int tid = threadIdx.x;
  int wv = tid >> 6, lane = tid & 63, quad = lane >> 4, l16 = lane & 15;
  int wn = wv * 64;                          // wave grid 1M x 2N; wm = 0
  int lin = blockIdx.y * 128 + blockIdx.x;
  int xcd = lin & 7, r = lin >> 3;           // r in 0..95
  int m0 = (xcd * 16 + (r & 15)) * 64;
  int n0 = (r >> 4) * 128;                   // 0..5
  f32x4 acc[4][4] = {};
  gemm_core<64, 128, 2>(A, Bt, As, Bs, m0, n0, tid, acc);

  for (int i = 0; i < 4; i++) {
    int row0 = m0 + i * 16 + quad * 4;
    for (int j = 0; j < 4; j++) {
      int n = n0 + wn + j * 16 + l16;
      float bias = bo[n];
      for (int r4 = 0; r4 < 4; r4++)
        out[(size_t)(row0 + r4) * EDIM + n] = acc[i][j][r4] + bias;
    }
  }
}

// ---------------- launch ----------------
extern "C" void kernel_launch(void* const* d_in, const int* in_sizes, int n_in,
                              void* d_out, int out_size, void* d_ws, size_t ws_size,
                              hipStream_t stream) {
  const float* x  = (const float*)d_in[0];
  const float* Wq = (const float*)d_in[1];
  const float* bq = (const float*)d_in[2];
  const float* Wk = (const float*)d_in[3];
  const float* bk = (const float*)d_in[4];
  const float* Wv = (const float*)d_in[5];
  const float* bv = (const float*)d_in[6];
  const float* Wo = (const float*)d_in[7];
  const float* bo = (const float*)d_in[8];
  float* out = (float*)d_out;
  char* ws = (char*)d_ws;

  u16* Xb   = (u16*)(ws);                      // 8192*768*2    = 12,582,912
  u16* Wt   = (u16*)(ws + 12582912);           // 2304*768*2    =  3,538,944
  u16* Wot  = (u16*)(ws + 16121856);           // 768*768*2     =  1,179,648
  u16* qkv  = (u16*)(ws + 17301504);           // 3*96*1024*64*2= 37,748,736
  u16* attn = (u16*)(ws + 55050240);           // 8192*768*2    = 12,582,912

  prep<<<6720, 256, 0, stream>>>(x, Xb, Wq, Wk, Wv, Wo, Wt, Wot);
  gemm_qkv<<<dim3(64, 18), 256, 0, stream>>>(Xb, Wt, bq, bk, bv, qkv);
  attn_kernel<<<dim3(96, 8), 256, 0, stream>>>(qkv, attn);
  gemm_out<<<dim3(128, 6), 128, 0, stream>>>(attn, Wot, bo, out);
}